// Round 16
// baseline (366.066 us; speedup 1.0000x reference)
//
#include <hip/hip_runtime.h>

typedef __attribute__((ext_vector_type(8))) short bf16x8;
typedef __attribute__((ext_vector_type(2))) unsigned uint2v;
typedef __attribute__((ext_vector_type(4))) float f32x4;

#define MFMA_BF16(a, b, c) __builtin_amdgcn_mfma_f32_16x16x32_bf16((a), (b), (c), 0, 0, 0)
#define VMCNT(N) asm volatile("s_waitcnt vmcnt(" #N ")" ::: "memory")
#define BAR() asm volatile("s_barrier" ::: "memory")

__device__ __forceinline__ unsigned short bf16rn(float f) {
  unsigned u = __builtin_bit_cast(unsigned, f);
  u += 0x7fffu + ((u >> 16) & 1u);
  return (unsigned short)(u >> 16);
}

__device__ __forceinline__ void gld_lds16(const void* g, void* l) {
  __builtin_amdgcn_global_load_lds((const __attribute__((address_space(1))) void*)g,
                                   (__attribute__((address_space(3))) void*)l, 16, 0, 0);
}

// ---------------- weight convert + transpose: W[K][N] f32 -> W^T[N][K] bf16 ----------------
__global__ __launch_bounds__(256) void convT_kernel(
    const float* __restrict__ wq, const float* __restrict__ wk,
    const float* __restrict__ wv, const float* __restrict__ wo,
    const float* __restrict__ wfc, const float* __restrict__ wpj,
    unsigned short* __restrict__ wsb)
{
  const int bid = blockIdx.x;
  const float* src; unsigned short* dst; int K, N, lb;
  if (bid < 1024) {
    const int m = bid >> 8; lb = bid & 255; K = 1024; N = 1024;
    src = (m == 0) ? wq : (m == 1) ? wk : (m == 2) ? wv : wo;
    dst = wsb + (size_t)m * 1048576u;
  } else if (bid < 2048) {
    lb = bid - 1024; K = 1024; N = 4096; src = wfc; dst = wsb + 4194304u;
  } else {
    lb = bid - 2048; K = 4096; N = 1024; src = wpj; dst = wsb + 8388608u;
  }
  const int tiles_k = K >> 6;
  const int tk = lb % tiles_k, tn = lb / tiles_k;
  const int k0 = tk << 6, n0 = tn << 6;
  const int t = threadIdx.x, kq = t & 15, nq = t >> 4;
  float4 r[4];
#pragma unroll
  for (int i = 0; i < 4; ++i)
    r[i] = *(const float4*)(src + (size_t)(k0 + kq * 4 + i) * N + n0 + nq * 4);
#pragma unroll
  for (int j = 0; j < 4; ++j) {
    ushort4 o;
    o.x = bf16rn(((const float*)&r[0])[j]);
    o.y = bf16rn(((const float*)&r[1])[j]);
    o.z = bf16rn(((const float*)&r[2])[j]);
    o.w = bf16rn(((const float*)&r[3])[j]);
    *(ushort4*)(dst + (size_t)(n0 + nq * 4 + j) * K + k0 + kq * 4) = o;
  }
}

// ---------------- layernorm: f32 [rows][1024] -> bf16 ----------------
__global__ __launch_bounds__(256) void ln_kernel(
    const float* __restrict__ x, const float* __restrict__ sc,
    const float* __restrict__ sh, unsigned short* __restrict__ out)
{
  const int row = blockIdx.x, t = threadIdx.x;
  const float4 v = *(const float4*)(x + (size_t)row * 1024 + t * 4);
  float s = v.x + v.y + v.z + v.w;
  float q = v.x * v.x + v.y * v.y + v.z * v.z + v.w * v.w;
#pragma unroll
  for (int off = 1; off < 64; off <<= 1) { s += __shfl_xor(s, off); q += __shfl_xor(q, off); }
  __shared__ float ps[4], pq[4];
  if ((t & 63) == 0) { ps[t >> 6] = s; pq[t >> 6] = q; }
  __syncthreads();
  s = ps[0] + ps[1] + ps[2] + ps[3];
  q = pq[0] + pq[1] + pq[2] + pq[3];
  const float mean = s * (1.f / 1024.f);
  const float var = q * (1.f / 1024.f) - mean * mean;
  const float inv = rsqrtf(var + 1e-5f);
  const float4 scv = *(const float4*)(sc + t * 4);
  const float4 shv = *(const float4*)(sh + t * 4);
  ushort4 o;
  o.x = bf16rn((v.x - mean) * inv * scv.x + shv.x);
  o.y = bf16rn((v.y - mean) * inv * scv.y + shv.y);
  o.z = bf16rn((v.z - mean) * inv * scv.z + shv.z);
  o.w = bf16rn((v.w - mean) * inv * scv.w + shv.w);
  *(ushort4*)(out + (size_t)row * 1024 + t * 4) = o;
}

// ---------------- 128x128 GEMM, kept only for V (EPI=1: transposed store) -----------------
template<int EPI>
__global__ __launch_bounds__(256) void gemm_bt(
    const unsigned short* __restrict__ A, const unsigned short* __restrict__ Bt,
    int M, int N, int K,
    unsigned short* __restrict__ outb, float* __restrict__ outf,
    const float* __restrict__ bias, const float* __restrict__ resid)
{
  __shared__ char smem[36864];
  const int t = threadIdx.x;
  const int lane = t & 63, w = t >> 6;
  const int g = lane >> 4, l15 = lane & 15;
  const int wr = w >> 1, wc = w & 1;
  const int bid = blockIdx.x;
  const int j = bid >> 3;
  const int tm = (bid & 7) * 8 + (j & 7);
  const int tn = j >> 3;
  const int m0 = tm * 128, n0 = tn * 128;

  f32x4 acc[4][4] = {};

  const int nkt = K >> 5;
  for (int kt = 0; kt < nkt; ++kt) {
    const int k0 = kt << 5;
    __syncthreads();
#pragma unroll
    for (int it = 0; it < 2; ++it) {
      const int c = it * 256 + t;
      const int row = c >> 2;
      const int ce = (c & 3) << 3;
      gld_lds16(A + (size_t)(m0 + row) * K + k0 + ce,
                smem + ((it * 256 + w * 64) << 4));
      gld_lds16(Bt + (size_t)(n0 + row) * K + k0 + ce,
                smem + 8192 + ((it * 256 + w * 64) << 4));
    }
    __syncthreads();
    bf16x8 a[4], b[4];
#pragma unroll
    for (int mi = 0; mi < 4; ++mi)
      a[mi] = *(const bf16x8*)(smem + (wr * 64 + mi * 16 + l15) * 64 + g * 16);
#pragma unroll
    for (int ni = 0; ni < 4; ++ni)
      b[ni] = *(const bf16x8*)(smem + 8192 + (wc * 64 + ni * 16 + l15) * 64 + g * 16);
#pragma unroll
    for (int mi = 0; mi < 4; ++mi)
#pragma unroll
      for (int ni = 0; ni < 4; ++ni)
        acc[mi][ni] = MFMA_BF16(a[mi], b[ni], acc[mi][ni]);
  }

  if constexpr (EPI == 1) {  // transposed store for V
    __syncthreads();
    unsigned short* T = (unsigned short*)(smem + w * 9216);  // [64 n][72 m-padded]
#pragma unroll
    for (int mi = 0; mi < 4; ++mi)
#pragma unroll
      for (int ni = 0; ni < 4; ++ni)
#pragma unroll
        for (int r = 0; r < 4; ++r)
          T[(ni * 16 + l15) * 72 + mi * 16 + 4 * g + r] = bf16rn(acc[mi][ni][r]);
    asm volatile("s_waitcnt lgkmcnt(0)" ::: "memory");
    const int bidx = m0 >> 11;
    const int srow = (m0 & 2047) + wr * 64 + ((lane & 7) << 3);
#pragma unroll
    for (int rr = 0; rr < 8; ++rr) {
      const int trow = rr * 8 + (lane >> 3);
      bf16x8 v = *(const bf16x8*)((char*)T + trow * 144 + ((lane & 7) << 4));
      *(bf16x8*)(outb + (size_t)(bidx * 1024 + n0 + wc * 64 + trow) * 2048 + srow) = v;
    }
  }
}

// ---------------- 128x128 BK=64 GEMM: 2 blocks/CU + quadrant phases + counted vmcnt ------
template<int EPI>
__global__ __launch_bounds__(256, 2) void g128(
    const unsigned short* __restrict__ A, const unsigned short* __restrict__ Bt,
    int N, int K,
    unsigned short* __restrict__ outb, float* __restrict__ outf,
    const float* __restrict__ bias, const float* __restrict__ resid)
{
  extern __shared__ char smem[];
  constexpr int BUFSZ = 32768;  // A 16KB + B 16KB
  const int t = threadIdx.x, lane = t & 63, w = t >> 6;
  const int g = lane >> 4, l15 = lane & 15;
  const int wr = w >> 1, wc = w & 1;  // 2M x 2N waves; wave tile 64 x 64
  const int bid = blockIdx.x;
  const int tm = (bid & 7) * 8 + ((bid >> 3) & 7);
  const int tn = bid >> 6;
  const int m0 = tm << 7, n0 = tn << 7;

  const int srow = t >> 3;
  const int colswz = (((t & 7) ^ (srow & 7)) << 3);
  const unsigned short* pA = A + (size_t)(m0 + srow) * K + colswz;
  const unsigned short* pB = Bt + (size_t)(n0 + srow) * K + colswz;
  const int ldw = w << 10;

  auto stA = [&](int TT, char* buf) {
#pragma unroll
    for (int i = 0; i < 4; ++i)
      gld_lds16(pA + TT * 64 + (size_t)(i * 32) * K, buf + i * 4096 + ldw);
  };
  auto stB02 = [&](int TT, char* buf) {
    gld_lds16(pB + TT * 64, buf + 16384 + ldw);
    gld_lds16(pB + TT * 64 + (size_t)64 * K, buf + 16384 + 8192 + ldw);
  };
  auto stB13 = [&](int TT, char* buf) {
    gld_lds16(pB + TT * 64 + (size_t)32 * K, buf + 16384 + 4096 + ldw);
    gld_lds16(pB + TT * 64 + (size_t)96 * K, buf + 16384 + 12288 + ldw);
  };

  const int sw0 = (((0 + g) ^ (l15 & 7)) << 4);
  const int sw1 = (((4 + g) ^ (l15 & 7)) << 4);
  const int NT = K >> 6;

  f32x4 acc[4][4] = {};
  bf16x8 av[4][2], bv0[2][2], bv1[2][2];

#define LDA_ALL(CB) { _Pragma("unroll") for (int mi = 0; mi < 4; ++mi) {                  \
    const int row_ = (wr * 64 + mi * 16 + l15) * 128;                                     \
    av[mi][0] = *(const bf16x8*)((CB) + row_ + sw0);                                      \
    av[mi][1] = *(const bf16x8*)((CB) + row_ + sw1); } }
#define LDB_H(CB, H, BV) { _Pragma("unroll") for (int ni = 0; ni < 2; ++ni) {             \
    const int row_ = 16384 + (wc * 64 + (H) * 32 + ni * 16 + l15) * 128;                  \
    BV[ni][0] = *(const bf16x8*)((CB) + row_ + sw0);                                      \
    BV[ni][1] = *(const bf16x8*)((CB) + row_ + sw1); } }
#define MMH(BV, H) { __builtin_amdgcn_s_setprio(1);                                       \
    _Pragma("unroll") for (int mi = 0; mi < 4; ++mi)                                      \
      _Pragma("unroll") for (int ni = 0; ni < 2; ++ni) {                                  \
        acc[mi][(H)*2+ni] = MFMA_BF16(av[mi][0], BV[ni][0], acc[mi][(H)*2+ni]);           \
        acc[mi][(H)*2+ni] = MFMA_BF16(av[mi][1], BV[ni][1], acc[mi][(H)*2+ni]);  }        \
    __builtin_amdgcn_s_setprio(0); }

  // prologue: full tile 0 (8 ops) + tile 1's A,B02 (6 ops); prove tile 0
  stA(0, smem); stB02(0, smem); stB13(0, smem);
  stA(1, smem + BUFSZ); stB02(1, smem + BUFSZ);
  VMCNT(6);
  BAR();

  for (int kt = 0; kt < NT; ++kt) {
    char* cb = smem + (kt & 1) * BUFSZ;
    char* ob = smem + ((kt & 1) ^ 1) * BUFSZ;
    LDA_ALL(cb);
    LDB_H(cb, 0, bv0);
    if (kt + 1 < NT) stB13(kt + 1, ob);
    BAR();
    MMH(bv0, 0);
    BAR();
    LDB_H(cb, 1, bv1);
    if (kt + 2 < NT) { stA(kt + 2, cb); stB02(kt + 2, cb); VMCNT(6); }
    else if (kt + 1 < NT) VMCNT(0);
    BAR();
    MMH(bv1, 1);
    BAR();
  }
#undef LDA_ALL
#undef LDB_H
#undef MMH

  if constexpr (EPI == 2) {
#pragma unroll
    for (int mi = 0; mi < 4; ++mi) {
      const int ro = mi * 16 + g * 4;
#pragma unroll
      for (int ci = 0; ci < 4; ++ci) {
        const int n = n0 + wc * 64 + ci * 16 + l15;
        const float bn = bias[n];
#pragma unroll
        for (int r = 0; r < 4; ++r) {
          const size_t m = m0 + wr * 64 + ro + r;
          outf[m * N + n] = acc[mi][ci][r] + bn + resid[m * N + n];
        }
      }
    }
  } else {
    __syncthreads();
    char* wsl = smem + w * 8192;  // per-wave bounce [64 rows][64 cols] bf16
#pragma unroll
    for (int mi = 0; mi < 4; ++mi) {
      const int ro = mi * 16 + g * 4;
#pragma unroll
      for (int ci = 0; ci < 4; ++ci) {
        const int co = ci * 16 + l15;
        float bn = 0.f;
        if constexpr (EPI == 3) bn = bias[n0 + wc * 64 + co];
#pragma unroll
        for (int r = 0; r < 4; ++r) {
          float v = acc[mi][ci][r];
          if constexpr (EPI == 3) {
            v += bn;
            // gelu(u) = u / (1 + exp2(-2.3022085*(u+0.044715u^3)))
            const float inner = v + 0.044715f * v * v * v;
            const float s = exp2f(-2.3022085f * inner);
            v = v / (1.0f + s);
          }
          *(unsigned short*)(wsl + (ro + r) * 128 + co * 2) = bf16rn(v);
        }
      }
    }
#pragma unroll
    for (int s = 0; s < 8; ++s) {
      const int row = s * 8 + (lane >> 3);
      bf16x8 vv = *(const bf16x8*)(wsl + row * 128 + (lane & 7) * 16);
      *(bf16x8*)(outb + (size_t)(m0 + wr * 64 + row) * N + n0 + wc * 64 + (lane & 7) * 8) = vv;
    }
  }
}

// ---------------- flash attention, causal, D=64, QB=128 (4 waves x 32 rows), KB=64 --------
// Grid 64 x 16: one q-tile per block (qt = 15 - y, big first), 4 blocks/CU.
// P path: Pt[kv][q] per wave, 72B row stride (8B-aligned). Write: per (mi,nb)
// 2x v_cvt_pk_bf16_f32 + 1 ds_write_b64 (4 q-adjacent values at row kv=nb*16+l15,
// cols mi*16+4g..+3). Read A-frag (mi,ks): pa[j] = Pt[ks*32+g*8+j][mi*16+l15]
// via 8 ds_read_u16 (imm offsets, stride 72B; banks 2-way = free).
__global__ __launch_bounds__(256) void attn_kernel(
    const unsigned short* __restrict__ qg, const unsigned short* __restrict__ kg,
    const unsigned short* __restrict__ vT, unsigned short* __restrict__ ctx)
{
  __shared__ char smem[34816];  // K 8KB | V_T 8KB | Pt 4 x 4608
  const int bh = blockIdx.x, b = bh >> 4, h = bh & 15;
  const int t = threadIdx.x, lane = t & 63, w = t >> 6, g = lane >> 4, l15 = lane & 15;
  char* Ks = smem;
  char* Vs = smem + 8192;
  char* Pt = smem + 16384 + w * 4608;  // per-wave [64 kv][72B]

  const float SC = 0.18033688011112042f;  // 0.125 * log2(e)

  const int qt = 15 - (int)blockIdx.y;  // big tiles dispatched first
  const int q0 = qt << 7;
  const int q0w = q0 + w * 32;

  bf16x8 qf[2][2];
#pragma unroll
  for (int mi = 0; mi < 2; ++mi)
#pragma unroll
    for (int ks = 0; ks < 2; ++ks)
      qf[mi][ks] = *(const bf16x8*)(qg + (size_t)(b * 2048 + q0w + mi * 16 + l15) * 2048 +
                                    h * 64 + ks * 32 + g * 8);

  f32x4 acc[2][4] = {};
  float lsum[2][4] = {};

  const int ntile = 2 * qt + 2;
  for (int kt = 0; kt < ntile; ++kt) {
    const int kv0 = kt << 6;
    __syncthreads();
#pragma unroll
    for (int it = 0; it < 2; ++it) {
      const int c = it * 256 + t;
      const int row = c >> 3;
      const int wb = (c & 7) << 4;
      const int sw = (wb ^ ((row & 7) << 4)) >> 1;
      gld_lds16(kg + (size_t)(b * 2048 + kv0 + row) * 2048 + h * 64 + sw,
                Ks + ((it * 256 + w * 64) << 4));
      gld_lds16(vT + (size_t)(b * 1024 + h * 64 + row) * 2048 + kv0 + sw,
                Vs + ((it * 256 + w * 64) << 4));
    }
    __syncthreads();

    f32x4 sf[2][4] = {};
#pragma unroll
    for (int nb = 0; nb < 4; ++nb) {
      const int krow = nb * 16 + l15;
#pragma unroll
      for (int ks = 0; ks < 2; ++ks) {
        bf16x8 kf = *(const bf16x8*)(Ks + krow * 128 +
                                     (((ks * 32 + g * 8) << 1) ^ ((krow & 7) << 4)));
        sf[0][nb] = MFMA_BF16(qf[0][ks], kf, sf[0][nb]);
        sf[1][nb] = MFMA_BF16(qf[1][ks], kf, sf[1][nb]);
      }
    }
    if (kv0 + 63 > q0w) {  // causal mask (wave-uniform branch)
#pragma unroll
      for (int mi = 0; mi < 2; ++mi)
#pragma unroll
        for (int nb = 0; nb < 4; ++nb)
#pragma unroll
          for (int r = 0; r < 4; ++r) {
            const int qq = q0w + mi * 16 + 4 * g + r;
            const int kk = kv0 + nb * 16 + l15;
            if (kk > qq) sf[mi][nb][r] = -__builtin_inff();
          }
    }
#pragma unroll
    for (int mi = 0; mi < 2; ++mi)
#pragma unroll
      for (int nb = 0; nb < 4; ++nb)
#pragma unroll
        for (int r = 0; r < 4; ++r) {
          const float p = exp2f(__builtin_fmaf(sf[mi][nb][r], SC, -4.0f));
          sf[mi][nb][r] = p;
          lsum[mi][r] += p;
        }
    // pack P -> Pt[kv][q]: per (mi,nb) one b64 of 4 q-adjacent bf16 (2x cvt_pk)
#pragma unroll
    for (int mi = 0; mi < 2; ++mi)
#pragma unroll
      for (int nb = 0; nb < 4; ++nb) {
        uint2v dw;
        asm("v_cvt_pk_bf16_f32 %0, %1, %2"
            : "=v"(dw.x) : "v"(sf[mi][nb][0]), "v"(sf[mi][nb][1]));
        asm("v_cvt_pk_bf16_f32 %0, %1, %2"
            : "=v"(dw.y) : "v"(sf[mi][nb][2]), "v"(sf[mi][nb][3]));
        *(uint2v*)(Pt + (nb * 16 + l15) * 72 + ((mi * 16 + 4 * g) << 1)) = dw;
      }
    asm volatile("s_waitcnt lgkmcnt(0)" ::: "memory");  // same-wave P RAW
#pragma unroll
    for (int mi = 0; mi < 2; ++mi)
#pragma unroll
      for (int ks = 0; ks < 2; ++ks) {
        const char* pp = Pt + (ks * 32 + g * 8) * 72 + ((mi * 16 + l15) << 1);
        bf16x8 pa;
#pragma unroll
        for (int jj = 0; jj < 8; ++jj)
          pa[jj] = *(const short*)(pp + jj * 72);
#pragma unroll
        for (int nb = 0; nb < 4; ++nb) {
          const int drow = nb * 16 + l15;
          bf16x8 vb = *(const bf16x8*)(Vs + drow * 128 +
                                       (((ks * 32 + g * 8) << 1) ^ ((drow & 7) << 4)));
          acc[mi][nb] = MFMA_BF16(pa, vb, acc[mi][nb]);
        }
      }
  }
  // one 16-lane sum reduce per q-row
#pragma unroll
  for (int mi = 0; mi < 2; ++mi)
#pragma unroll
    for (int r = 0; r < 4; ++r) {
      float s = lsum[mi][r];
      s += __shfl_xor(s, 1);
      s += __shfl_xor(s, 2);
      s += __shfl_xor(s, 4);
      s += __shfl_xor(s, 8);
      lsum[mi][r] = s;
    }
#pragma unroll
  for (int mi = 0; mi < 2; ++mi) {
    float inv[4];
#pragma unroll
    for (int r = 0; r < 4; ++r) inv[r] = 1.0f / lsum[mi][r];
#pragma unroll
    for (int nb = 0; nb < 4; ++nb)
#pragma unroll
      for (int r = 0; r < 4; ++r)
        ctx[(size_t)(b * 2048 + q0w + mi * 16 + 4 * g + r) * 1024 + h * 64 + nb * 16 + l15] =
            bf16rn(acc[mi][nb][r] * inv[r]);
  }
}

extern "C" void kernel_launch(void* const* d_in, const int* in_sizes, int n_in,
                              void* d_out, int out_size, void* d_ws, size_t ws_size,
                              hipStream_t stream)
{
  const float* x   = (const float*)d_in[0];
  const float* l1s = (const float*)d_in[1];
  const float* l1b = (const float*)d_in[2];
  const float* l2s = (const float*)d_in[3];
  const float* l2b = (const float*)d_in[4];
  const float* Wq  = (const float*)d_in[5];
  const float* Wk  = (const float*)d_in[6];
  const float* Wv  = (const float*)d_in[7];
  const float* Wo  = (const float*)d_in[8];
  const float* bo  = (const float*)d_in[9];
  const float* Wfc = (const float*)d_in[10];
  const float* bfc = (const float*)d_in[11];
  const float* Wpj = (const float*)d_in[12];
  const float* bpj = (const float*)d_in[13];
  float* out = (float*)d_out;
  char* ws = (char*)d_ws;

  unsigned short* wT   = (unsigned short*)ws;                // 24MB weights
  unsigned short* wqkT = wT;                                 // [2048][1024] fused Q|K
  unsigned short* wvT  = wT + 2097152u;
  unsigned short* woT  = wT + 3145728u;
  unsigned short* wfcT = wT + 4194304u;
  unsigned short* wpjT = wT + 8388608u;
  unsigned short* ln1x = (unsigned short*)(ws + 25165824u);  // 16MB
  unsigned short* qkb  = (unsigned short*)(ws + 41943040u);  // 32MB [8192][2048]
  unsigned short* vTb  = (unsigned short*)(ws + 75497472u);  // 16MB
  unsigned short* ctx  = (unsigned short*)(ws + 92274688u);  // 16MB (reused as ln2x)
  unsigned short* ln2x = ctx;
  float* hbuf          = (float*)(ws + 109051904u);          // 32MB
  unsigned short* fcb  = (unsigned short*)(ws + 25165824u);  // 64MB, reuses ln1x..vTb

  convT_kernel<<<3072, 256, 0, stream>>>(Wq, Wk, Wv, Wo, Wfc, Wpj, wT);
  ln_kernel<<<8192, 256, 0, stream>>>(x, l1s, l1b, ln1x);
  g128<0><<<1024, 256, 65536, stream>>>(ln1x, wqkT, 2048, 1024,
                                        qkb, nullptr, nullptr, nullptr);
  gemm_bt<1><<<512, 256, 0, stream>>>(ln1x, wvT, 8192, 1024, 1024,
                                      vTb, nullptr, nullptr, nullptr);
  attn_kernel<<<dim3(64, 16), 256, 0, stream>>>(qkb, qkb + 1024, vTb, ctx);
  g128<2><<<512, 256, 65536, stream>>>(ctx, woT, 1024, 1024,
                                       nullptr, hbuf, bo, x);
  ln_kernel<<<8192, 256, 0, stream>>>(hbuf, l2s, l2b, ln2x);
  g128<3><<<2048, 256, 65536, stream>>>(ln2x, wfcT, 4096, 1024,
                                        fcb, nullptr, bfc, nullptr);
  g128<2><<<512, 256, 65536, stream>>>(fcb, wpjT, 1024, 4096,
                                       nullptr, out, bpj, hbuf);
}

// Round 17
// 346.159 us; speedup vs baseline: 1.0575x; 1.0575x over previous
//
#include <hip/hip_runtime.h>

typedef __attribute__((ext_vector_type(8))) short bf16x8;
typedef __attribute__((ext_vector_type(2))) unsigned uint2v;
typedef __attribute__((ext_vector_type(4))) float f32x4;

#define MFMA_BF16(a, b, c) __builtin_amdgcn_mfma_f32_16x16x32_bf16((a), (b), (c), 0, 0, 0)
#define VMCNT(N) asm volatile("s_waitcnt vmcnt(" #N ")" ::: "memory")
#define BAR() asm volatile("s_barrier" ::: "memory")

__device__ __forceinline__ unsigned short bf16rn(float f) {
  unsigned u = __builtin_bit_cast(unsigned, f);
  u += 0x7fffu + ((u >> 16) & 1u);
  return (unsigned short)(u >> 16);
}

__device__ __forceinline__ void gld_lds16(const void* g, void* l) {
  __builtin_amdgcn_global_load_lds((const __attribute__((address_space(1))) void*)g,
                                   (__attribute__((address_space(3))) void*)l, 16, 0, 0);
}

// ---------------- weight convert + transpose: W[K][N] f32 -> W^T[N][K] bf16 ----------------
__global__ __launch_bounds__(256) void convT_kernel(
    const float* __restrict__ wq, const float* __restrict__ wk,
    const float* __restrict__ wv, const float* __restrict__ wo,
    const float* __restrict__ wfc, const float* __restrict__ wpj,
    unsigned short* __restrict__ wsb)
{
  const int bid = blockIdx.x;
  const float* src; unsigned short* dst; int K, N, lb;
  if (bid < 1024) {
    const int m = bid >> 8; lb = bid & 255; K = 1024; N = 1024;
    src = (m == 0) ? wq : (m == 1) ? wk : (m == 2) ? wv : wo;
    dst = wsb + (size_t)m * 1048576u;
  } else if (bid < 2048) {
    lb = bid - 1024; K = 1024; N = 4096; src = wfc; dst = wsb + 4194304u;
  } else {
    lb = bid - 2048; K = 4096; N = 1024; src = wpj; dst = wsb + 8388608u;
  }
  const int tiles_k = K >> 6;
  const int tk = lb % tiles_k, tn = lb / tiles_k;
  const int k0 = tk << 6, n0 = tn << 6;
  const int t = threadIdx.x, kq = t & 15, nq = t >> 4;
  float4 r[4];
#pragma unroll
  for (int i = 0; i < 4; ++i)
    r[i] = *(const float4*)(src + (size_t)(k0 + kq * 4 + i) * N + n0 + nq * 4);
#pragma unroll
  for (int j = 0; j < 4; ++j) {
    ushort4 o;
    o.x = bf16rn(((const float*)&r[0])[j]);
    o.y = bf16rn(((const float*)&r[1])[j]);
    o.z = bf16rn(((const float*)&r[2])[j]);
    o.w = bf16rn(((const float*)&r[3])[j]);
    *(ushort4*)(dst + (size_t)(n0 + nq * 4 + j) * K + k0 + kq * 4) = o;
  }
}

// ---------------- layernorm: f32 [rows][1024] -> bf16 ----------------
__global__ __launch_bounds__(256) void ln_kernel(
    const float* __restrict__ x, const float* __restrict__ sc,
    const float* __restrict__ sh, unsigned short* __restrict__ out)
{
  const int row = blockIdx.x, t = threadIdx.x;
  const float4 v = *(const float4*)(x + (size_t)row * 1024 + t * 4);
  float s = v.x + v.y + v.z + v.w;
  float q = v.x * v.x + v.y * v.y + v.z * v.z + v.w * v.w;
#pragma unroll
  for (int off = 1; off < 64; off <<= 1) { s += __shfl_xor(s, off); q += __shfl_xor(q, off); }
  __shared__ float ps[4], pq[4];
  if ((t & 63) == 0) { ps[t >> 6] = s; pq[t >> 6] = q; }
  __syncthreads();
  s = ps[0] + ps[1] + ps[2] + ps[3];
  q = pq[0] + pq[1] + pq[2] + pq[3];
  const float mean = s * (1.f / 1024.f);
  const float var = q * (1.f / 1024.f) - mean * mean;
  const float inv = rsqrtf(var + 1e-5f);
  const float4 scv = *(const float4*)(sc + t * 4);
  const float4 shv = *(const float4*)(sh + t * 4);
  ushort4 o;
  o.x = bf16rn((v.x - mean) * inv * scv.x + shv.x);
  o.y = bf16rn((v.y - mean) * inv * scv.y + shv.y);
  o.z = bf16rn((v.z - mean) * inv * scv.z + shv.z);
  o.w = bf16rn((v.w - mean) * inv * scv.w + shv.w);
  *(ushort4*)(out + (size_t)row * 1024 + t * 4) = o;
}

// ---------------- 128x128 GEMM, kept only for V (EPI=1: transposed store) -----------------
template<int EPI>
__global__ __launch_bounds__(256) void gemm_bt(
    const unsigned short* __restrict__ A, const unsigned short* __restrict__ Bt,
    int M, int N, int K,
    unsigned short* __restrict__ outb, float* __restrict__ outf,
    const float* __restrict__ bias, const float* __restrict__ resid)
{
  __shared__ char smem[36864];
  const int t = threadIdx.x;
  const int lane = t & 63, w = t >> 6;
  const int g = lane >> 4, l15 = lane & 15;
  const int wr = w >> 1, wc = w & 1;
  const int bid = blockIdx.x;
  const int j = bid >> 3;
  const int tm = (bid & 7) * 8 + (j & 7);
  const int tn = j >> 3;
  const int m0 = tm * 128, n0 = tn * 128;

  f32x4 acc[4][4] = {};

  const int nkt = K >> 5;
  for (int kt = 0; kt < nkt; ++kt) {
    const int k0 = kt << 5;
    __syncthreads();
#pragma unroll
    for (int it = 0; it < 2; ++it) {
      const int c = it * 256 + t;
      const int row = c >> 2;
      const int ce = (c & 3) << 3;
      gld_lds16(A + (size_t)(m0 + row) * K + k0 + ce,
                smem + ((it * 256 + w * 64) << 4));
      gld_lds16(Bt + (size_t)(n0 + row) * K + k0 + ce,
                smem + 8192 + ((it * 256 + w * 64) << 4));
    }
    __syncthreads();
    bf16x8 a[4], b[4];
#pragma unroll
    for (int mi = 0; mi < 4; ++mi)
      a[mi] = *(const bf16x8*)(smem + (wr * 64 + mi * 16 + l15) * 64 + g * 16);
#pragma unroll
    for (int ni = 0; ni < 4; ++ni)
      b[ni] = *(const bf16x8*)(smem + 8192 + (wc * 64 + ni * 16 + l15) * 64 + g * 16);
#pragma unroll
    for (int mi = 0; mi < 4; ++mi)
#pragma unroll
      for (int ni = 0; ni < 4; ++ni)
        acc[mi][ni] = MFMA_BF16(a[mi], b[ni], acc[mi][ni]);
  }

  if constexpr (EPI == 1) {  // transposed store for V
    __syncthreads();
    unsigned short* T = (unsigned short*)(smem + w * 9216);  // [64 n][72 m-padded]
#pragma unroll
    for (int mi = 0; mi < 4; ++mi)
#pragma unroll
      for (int ni = 0; ni < 4; ++ni)
#pragma unroll
        for (int r = 0; r < 4; ++r)
          T[(ni * 16 + l15) * 72 + mi * 16 + 4 * g + r] = bf16rn(acc[mi][ni][r]);
    asm volatile("s_waitcnt lgkmcnt(0)" ::: "memory");
    const int bidx = m0 >> 11;
    const int srow = (m0 & 2047) + wr * 64 + ((lane & 7) << 3);
#pragma unroll
    for (int rr = 0; rr < 8; ++rr) {
      const int trow = rr * 8 + (lane >> 3);
      bf16x8 v = *(const bf16x8*)((char*)T + trow * 144 + ((lane & 7) << 4));
      *(bf16x8*)(outb + (size_t)(bidx * 1024 + n0 + wc * 64 + trow) * 2048 + srow) = v;
    }
  }
}

// ---------------- 128x128 BK=64 GEMM: 2 blocks/CU + quadrant phases + counted vmcnt ------
template<int EPI>
__global__ __launch_bounds__(256, 2) void g128(
    const unsigned short* __restrict__ A, const unsigned short* __restrict__ Bt,
    int N, int K,
    unsigned short* __restrict__ outb, float* __restrict__ outf,
    const float* __restrict__ bias, const float* __restrict__ resid)
{
  extern __shared__ char smem[];
  constexpr int BUFSZ = 32768;  // A 16KB + B 16KB
  const int t = threadIdx.x, lane = t & 63, w = t >> 6;
  const int g = lane >> 4, l15 = lane & 15;
  const int wr = w >> 1, wc = w & 1;  // 2M x 2N waves; wave tile 64 x 64
  const int bid = blockIdx.x;
  const int tm = (bid & 7) * 8 + ((bid >> 3) & 7);
  const int tn = bid >> 6;
  const int m0 = tm << 7, n0 = tn << 7;

  const int srow = t >> 3;
  const int colswz = (((t & 7) ^ (srow & 7)) << 3);
  const unsigned short* pA = A + (size_t)(m0 + srow) * K + colswz;
  const unsigned short* pB = Bt + (size_t)(n0 + srow) * K + colswz;
  const int ldw = w << 10;

  auto stA = [&](int TT, char* buf) {
#pragma unroll
    for (int i = 0; i < 4; ++i)
      gld_lds16(pA + TT * 64 + (size_t)(i * 32) * K, buf + i * 4096 + ldw);
  };
  auto stB02 = [&](int TT, char* buf) {
    gld_lds16(pB + TT * 64, buf + 16384 + ldw);
    gld_lds16(pB + TT * 64 + (size_t)64 * K, buf + 16384 + 8192 + ldw);
  };
  auto stB13 = [&](int TT, char* buf) {
    gld_lds16(pB + TT * 64 + (size_t)32 * K, buf + 16384 + 4096 + ldw);
    gld_lds16(pB + TT * 64 + (size_t)96 * K, buf + 16384 + 12288 + ldw);
  };

  const int sw0 = (((0 + g) ^ (l15 & 7)) << 4);
  const int sw1 = (((4 + g) ^ (l15 & 7)) << 4);
  const int NT = K >> 6;

  f32x4 acc[4][4] = {};
  bf16x8 av[4][2], bv0[2][2], bv1[2][2];

#define LDA_ALL(CB) { _Pragma("unroll") for (int mi = 0; mi < 4; ++mi) {                  \
    const int row_ = (wr * 64 + mi * 16 + l15) * 128;                                     \
    av[mi][0] = *(const bf16x8*)((CB) + row_ + sw0);                                      \
    av[mi][1] = *(const bf16x8*)((CB) + row_ + sw1); } }
#define LDB_H(CB, H, BV) { _Pragma("unroll") for (int ni = 0; ni < 2; ++ni) {             \
    const int row_ = 16384 + (wc * 64 + (H) * 32 + ni * 16 + l15) * 128;                  \
    BV[ni][0] = *(const bf16x8*)((CB) + row_ + sw0);                                      \
    BV[ni][1] = *(const bf16x8*)((CB) + row_ + sw1); } }
#define MMH(BV, H) { __builtin_amdgcn_s_setprio(1);                                       \
    _Pragma("unroll") for (int mi = 0; mi < 4; ++mi)                                      \
      _Pragma("unroll") for (int ni = 0; ni < 2; ++ni) {                                  \
        acc[mi][(H)*2+ni] = MFMA_BF16(av[mi][0], BV[ni][0], acc[mi][(H)*2+ni]);           \
        acc[mi][(H)*2+ni] = MFMA_BF16(av[mi][1], BV[ni][1], acc[mi][(H)*2+ni]);  }        \
    __builtin_amdgcn_s_setprio(0); }

  // prologue: full tile 0 (8 ops) + tile 1's A,B02 (6 ops); prove tile 0
  stA(0, smem); stB02(0, smem); stB13(0, smem);
  stA(1, smem + BUFSZ); stB02(1, smem + BUFSZ);
  VMCNT(6);
  BAR();

  for (int kt = 0; kt < NT; ++kt) {
    char* cb = smem + (kt & 1) * BUFSZ;
    char* ob = smem + ((kt & 1) ^ 1) * BUFSZ;
    LDA_ALL(cb);
    LDB_H(cb, 0, bv0);
    if (kt + 1 < NT) stB13(kt + 1, ob);
    BAR();
    MMH(bv0, 0);
    BAR();
    LDB_H(cb, 1, bv1);
    if (kt + 2 < NT) { stA(kt + 2, cb); stB02(kt + 2, cb); VMCNT(6); }
    else if (kt + 1 < NT) VMCNT(0);
    BAR();
    MMH(bv1, 1);
    BAR();
  }
#undef LDA_ALL
#undef LDB_H
#undef MMH

  if constexpr (EPI == 2) {
#pragma unroll
    for (int mi = 0; mi < 4; ++mi) {
      const int ro = mi * 16 + g * 4;
#pragma unroll
      for (int ci = 0; ci < 4; ++ci) {
        const int n = n0 + wc * 64 + ci * 16 + l15;
        const float bn = bias[n];
#pragma unroll
        for (int r = 0; r < 4; ++r) {
          const size_t m = m0 + wr * 64 + ro + r;
          outf[m * N + n] = acc[mi][ci][r] + bn + resid[m * N + n];
        }
      }
    }
  } else {
    __syncthreads();
    char* wsl = smem + w * 8192;  // per-wave bounce [64 rows][64 cols] bf16
#pragma unroll
    for (int mi = 0; mi < 4; ++mi) {
      const int ro = mi * 16 + g * 4;
#pragma unroll
      for (int ci = 0; ci < 4; ++ci) {
        const int co = ci * 16 + l15;
        float bn = 0.f;
        if constexpr (EPI == 3) bn = bias[n0 + wc * 64 + co];
#pragma unroll
        for (int r = 0; r < 4; ++r) {
          float v = acc[mi][ci][r];
          if constexpr (EPI == 3) {
            v += bn;
            // gelu(u) = u / (1 + exp2(-2.3022085*(u+0.044715u^3)))
            const float inner = v + 0.044715f * v * v * v;
            const float s = exp2f(-2.3022085f * inner);
            v = v / (1.0f + s);
          }
          *(unsigned short*)(wsl + (ro + r) * 128 + co * 2) = bf16rn(v);
        }
      }
    }
#pragma unroll
    for (int s = 0; s < 8; ++s) {
      const int row = s * 8 + (lane >> 3);
      bf16x8 vv = *(const bf16x8*)(wsl + row * 128 + (lane & 7) * 16);
      *(bf16x8*)(outb + (size_t)(m0 + wr * 64 + row) * N + n0 + wc * 64 + (lane & 7) * 8) = vv;
    }
  }
}

// ---------------- flash attention, causal, D=64, QB=128 (8 waves x 16 rows), KB=64 --------
// 512 thr / 8 waves; K/V staging shared by all 8 waves (16 waves/CU at 2 blocks/CU).
// Per wave: 16 q-rows (A-frag row=l15, k=g*8+j; C/D row=4g+r, col=l15). Uniform pairing
// (qt = y, 15-y). Pt per wave [64 kv][40B]: write per nb = 2x cvt_pk + 1 ds_write_b64
// at (nb*16+l15)*40 + 8g; read pa[j] = Pt[(ks*32+g*8+j)*40 + l15*2].
__global__ __launch_bounds__(512) void attn_kernel(
    const unsigned short* __restrict__ qg, const unsigned short* __restrict__ kg,
    const unsigned short* __restrict__ vT, unsigned short* __restrict__ ctx)
{
  __shared__ char smem[36864];  // K 8KB | V 8KB | Pt 8 x 2560
  const int bh = blockIdx.x, b = bh >> 4, h = bh & 15;
  const int t = threadIdx.x, lane = t & 63, w = t >> 6, g = lane >> 4, l15 = lane & 15;
  char* Ks = smem;
  char* Vs = smem + 8192;
  char* Pt = smem + 16384 + w * 2560;  // per-wave [64 kv][40B]

  const float SC = 0.18033688011112042f;  // 0.125 * log2(e)

  // staging indices (512 threads cover 64 rows x 8 slots, swizzled source col)
  const int srow = t >> 3;
  const int ssw = ((((t & 7) << 4) ^ ((srow & 7) << 4)) >> 1);

  for (int pass = 0; pass < 2; ++pass) {
    const int qt = pass ? 15 - (int)blockIdx.y : (int)blockIdx.y;
    const int q0 = qt << 7;
    const int q0w = q0 + w * 16;

    bf16x8 qf[2];
#pragma unroll
    for (int ks = 0; ks < 2; ++ks)
      qf[ks] = *(const bf16x8*)(qg + (size_t)(b * 2048 + q0w + l15) * 2048 +
                                h * 64 + ks * 32 + g * 8);

    f32x4 acc[4] = {};
    float lsum[4] = {};

    const int ntile = 2 * qt + 2;
    for (int kt = 0; kt < ntile; ++kt) {
      const int kv0 = kt << 6;
      __syncthreads();
      gld_lds16(kg + (size_t)(b * 2048 + kv0 + srow) * 2048 + h * 64 + ssw,
                Ks + ((t >> 3) << 7));
      gld_lds16(vT + (size_t)(b * 1024 + h * 64 + srow) * 2048 + kv0 + ssw,
                Vs + ((t >> 3) << 7));
      __syncthreads();

      f32x4 sf[4] = {};
#pragma unroll
      for (int nb = 0; nb < 4; ++nb) {
        const int krow = nb * 16 + l15;
#pragma unroll
        for (int ks = 0; ks < 2; ++ks) {
          bf16x8 kf = *(const bf16x8*)(Ks + krow * 128 +
                                       (((ks * 32 + g * 8) << 1) ^ ((krow & 7) << 4)));
          sf[nb] = MFMA_BF16(qf[ks], kf, sf[nb]);
        }
      }
      if (kv0 + 63 > q0w) {  // causal mask (wave-uniform branch)
#pragma unroll
        for (int nb = 0; nb < 4; ++nb)
#pragma unroll
          for (int r = 0; r < 4; ++r) {
            const int qq = q0w + 4 * g + r;
            const int kk = kv0 + nb * 16 + l15;
            if (kk > qq) sf[nb][r] = -__builtin_inff();
          }
      }
#pragma unroll
      for (int nb = 0; nb < 4; ++nb)
#pragma unroll
        for (int r = 0; r < 4; ++r) {
          const float p = exp2f(__builtin_fmaf(sf[nb][r], SC, -4.0f));
          sf[nb][r] = p;
          lsum[r] += p;
        }
      // pack P -> Pt[kv][q16]: one b64 per nb (4 q-adjacent bf16)
#pragma unroll
      for (int nb = 0; nb < 4; ++nb) {
        uint2v dw;
        asm("v_cvt_pk_bf16_f32 %0, %1, %2"
            : "=v"(dw.x) : "v"(sf[nb][0]), "v"(sf[nb][1]));
        asm("v_cvt_pk_bf16_f32 %0, %1, %2"
            : "=v"(dw.y) : "v"(sf[nb][2]), "v"(sf[nb][3]));
        *(uint2v*)(Pt + (nb * 16 + l15) * 40 + (g << 3)) = dw;
      }
      asm volatile("s_waitcnt lgkmcnt(0)" ::: "memory");  // same-wave P RAW
#pragma unroll
      for (int ks = 0; ks < 2; ++ks) {
        const char* pp = Pt + (ks * 32 + g * 8) * 40 + (l15 << 1);
        bf16x8 pa;
#pragma unroll
        for (int jj = 0; jj < 8; ++jj)
          pa[jj] = *(const short*)(pp + jj * 40);
#pragma unroll
        for (int nb = 0; nb < 4; ++nb) {
          const int drow = nb * 16 + l15;
          bf16x8 vb = *(const bf16x8*)(Vs + drow * 128 +
                                       (((ks * 32 + g * 8) << 1) ^ ((drow & 7) << 4)));
          acc[nb] = MFMA_BF16(pa, vb, acc[nb]);
        }
      }
    }
    // one 16-lane sum reduce per q-row
#pragma unroll
    for (int r = 0; r < 4; ++r) {
      float s = lsum[r];
      s += __shfl_xor(s, 1);
      s += __shfl_xor(s, 2);
      s += __shfl_xor(s, 4);
      s += __shfl_xor(s, 8);
      lsum[r] = s;
    }
    float inv[4];
#pragma unroll
    for (int r = 0; r < 4; ++r) inv[r] = 1.0f / lsum[r];
#pragma unroll
    for (int nb = 0; nb < 4; ++nb)
#pragma unroll
      for (int r = 0; r < 4; ++r)
        ctx[(size_t)(b * 2048 + q0w + 4 * g + r) * 1024 + h * 64 + nb * 16 + l15] =
            bf16rn(acc[nb][r] * inv[r]);
  }
}

extern "C" void kernel_launch(void* const* d_in, const int* in_sizes, int n_in,
                              void* d_out, int out_size, void* d_ws, size_t ws_size,
                              hipStream_t stream)
{
  const float* x   = (const float*)d_in[0];
  const float* l1s = (const float*)d_in[1];
  const float* l1b = (const float*)d_in[2];
  const float* l2s = (const float*)d_in[3];
  const float* l2b = (const float*)d_in[4];
  const float* Wq  = (const float*)d_in[5];
  const float* Wk  = (const float*)d_in[6];
  const float* Wv  = (const float*)d_in[7];
  const float* Wo  = (const float*)d_in[8];
  const float* bo  = (const float*)d_in[9];
  const float* Wfc = (const float*)d_in[10];
  const float* bfc = (const float*)d_in[11];
  const float* Wpj = (const float*)d_in[12];
  const float* bpj = (const float*)d_in[13];
  float* out = (float*)d_out;
  char* ws = (char*)d_ws;

  unsigned short* wT   = (unsigned short*)ws;                // 24MB weights
  unsigned short* wqkT = wT;                                 // [2048][1024] fused Q|K
  unsigned short* wvT  = wT + 2097152u;
  unsigned short* woT  = wT + 3145728u;
  unsigned short* wfcT = wT + 4194304u;
  unsigned short* wpjT = wT + 8388608u;
  unsigned short* ln1x = (unsigned short*)(ws + 25165824u);  // 16MB
  unsigned short* qkb  = (unsigned short*)(ws + 41943040u);  // 32MB [8192][2048]
  unsigned short* vTb  = (unsigned short*)(ws + 75497472u);  // 16MB
  unsigned short* ctx  = (unsigned short*)(ws + 92274688u);  // 16MB (reused as ln2x)
  unsigned short* ln2x = ctx;
  float* hbuf          = (float*)(ws + 109051904u);          // 32MB
  unsigned short* fcb  = (unsigned short*)(ws + 25165824u);  // 64MB, reuses ln1x..vTb

  convT_kernel<<<3072, 256, 0, stream>>>(Wq, Wk, Wv, Wo, Wfc, Wpj, wT);
  ln_kernel<<<8192, 256, 0, stream>>>(x, l1s, l1b, ln1x);
  g128<0><<<1024, 256, 65536, stream>>>(ln1x, wqkT, 2048, 1024,
                                        qkb, nullptr, nullptr, nullptr);
  gemm_bt<1><<<512, 256, 0, stream>>>(ln1x, wvT, 8192, 1024, 1024,
                                      vTb, nullptr, nullptr, nullptr);
  attn_kernel<<<dim3(64, 8), 512, 0, stream>>>(qkb, qkb + 1024, vTb, ctx);
  g128<2><<<512, 256, 65536, stream>>>(ctx, woT, 1024, 1024,
                                       nullptr, hbuf, bo, x);
  ln_kernel<<<8192, 256, 0, stream>>>(hbuf, l2s, l2b, ln2x);
  g128<3><<<2048, 256, 65536, stream>>>(ln2x, wfcT, 4096, 1024,
                                        fcb, nullptr, bfc, nullptr);
  g128<2><<<512, 256, 65536, stream>>>(fcb, wpjT, 1024, 4096,
                                       nullptr, out, bpj, hbuf);
}

// Round 18
// 338.144 us; speedup vs baseline: 1.0826x; 1.0237x over previous
//
#include <hip/hip_runtime.h>

typedef __attribute__((ext_vector_type(8))) short bf16x8;
typedef __attribute__((ext_vector_type(2))) unsigned uint2v;
typedef __attribute__((ext_vector_type(4))) float f32x4;

#define MFMA_BF16(a, b, c) __builtin_amdgcn_mfma_f32_16x16x32_bf16((a), (b), (c), 0, 0, 0)
#define VMCNT(N) asm volatile("s_waitcnt vmcnt(" #N ")" ::: "memory")
#define BAR() asm volatile("s_barrier" ::: "memory")

__device__ __forceinline__ unsigned short bf16rn(float f) {
  unsigned u = __builtin_bit_cast(unsigned, f);
  u += 0x7fffu + ((u >> 16) & 1u);
  return (unsigned short)(u >> 16);
}

__device__ __forceinline__ void gld_lds16(const void* g, void* l) {
  __builtin_amdgcn_global_load_lds((const __attribute__((address_space(1))) void*)g,
                                   (__attribute__((address_space(3))) void*)l, 16, 0, 0);
}

// ---------------- weight convert + transpose: W[K][N] f32 -> W^T[N][K] bf16 ----------------
__global__ __launch_bounds__(256) void convT_kernel(
    const float* __restrict__ wq, const float* __restrict__ wk,
    const float* __restrict__ wv, const float* __restrict__ wo,
    const float* __restrict__ wfc, const float* __restrict__ wpj,
    unsigned short* __restrict__ wsb)
{
  const int bid = blockIdx.x;
  const float* src; unsigned short* dst; int K, N, lb;
  if (bid < 1024) {
    const int m = bid >> 8; lb = bid & 255; K = 1024; N = 1024;
    src = (m == 0) ? wq : (m == 1) ? wk : (m == 2) ? wv : wo;
    dst = wsb + (size_t)m * 1048576u;
  } else if (bid < 2048) {
    lb = bid - 1024; K = 1024; N = 4096; src = wfc; dst = wsb + 4194304u;
  } else {
    lb = bid - 2048; K = 4096; N = 1024; src = wpj; dst = wsb + 8388608u;
  }
  const int tiles_k = K >> 6;
  const int tk = lb % tiles_k, tn = lb / tiles_k;
  const int k0 = tk << 6, n0 = tn << 6;
  const int t = threadIdx.x, kq = t & 15, nq = t >> 4;
  float4 r[4];
#pragma unroll
  for (int i = 0; i < 4; ++i)
    r[i] = *(const float4*)(src + (size_t)(k0 + kq * 4 + i) * N + n0 + nq * 4);
#pragma unroll
  for (int j = 0; j < 4; ++j) {
    ushort4 o;
    o.x = bf16rn(((const float*)&r[0])[j]);
    o.y = bf16rn(((const float*)&r[1])[j]);
    o.z = bf16rn(((const float*)&r[2])[j]);
    o.w = bf16rn(((const float*)&r[3])[j]);
    *(ushort4*)(dst + (size_t)(n0 + nq * 4 + j) * K + k0 + kq * 4) = o;
  }
}

// ---------------- layernorm: f32 [rows][1024] -> bf16 ----------------
__global__ __launch_bounds__(256) void ln_kernel(
    const float* __restrict__ x, const float* __restrict__ sc,
    const float* __restrict__ sh, unsigned short* __restrict__ out)
{
  const int row = blockIdx.x, t = threadIdx.x;
  const float4 v = *(const float4*)(x + (size_t)row * 1024 + t * 4);
  float s = v.x + v.y + v.z + v.w;
  float q = v.x * v.x + v.y * v.y + v.z * v.z + v.w * v.w;
#pragma unroll
  for (int off = 1; off < 64; off <<= 1) { s += __shfl_xor(s, off); q += __shfl_xor(q, off); }
  __shared__ float ps[4], pq[4];
  if ((t & 63) == 0) { ps[t >> 6] = s; pq[t >> 6] = q; }
  __syncthreads();
  s = ps[0] + ps[1] + ps[2] + ps[3];
  q = pq[0] + pq[1] + pq[2] + pq[3];
  const float mean = s * (1.f / 1024.f);
  const float var = q * (1.f / 1024.f) - mean * mean;
  const float inv = rsqrtf(var + 1e-5f);
  const float4 scv = *(const float4*)(sc + t * 4);
  const float4 shv = *(const float4*)(sh + t * 4);
  ushort4 o;
  o.x = bf16rn((v.x - mean) * inv * scv.x + shv.x);
  o.y = bf16rn((v.y - mean) * inv * scv.y + shv.y);
  o.z = bf16rn((v.z - mean) * inv * scv.z + shv.z);
  o.w = bf16rn((v.w - mean) * inv * scv.w + shv.w);
  *(ushort4*)(out + (size_t)row * 1024 + t * 4) = o;
}

// ---------------- 128x128 BK=64 GEMM: 2 blocks/CU + quadrant phases + counted vmcnt ------
// EPI 0: bf16; 1: bf16 transposed into v_T[b*1024+n][2048]; 2: f32 = acc+bias+resid;
// 3: bf16 = gelu(acc+bias). Epilogue bounce rows byte-rotated by g*32 (write) /
// ((row>>2)&3)*32 (read) -> write 2-way (free); rotation cancels in read-chunk mapping.
template<int EPI>
__global__ __launch_bounds__(256, 2) void g128(
    const unsigned short* __restrict__ A, const unsigned short* __restrict__ Bt,
    int N, int K,
    unsigned short* __restrict__ outb, float* __restrict__ outf,
    const float* __restrict__ bias, const float* __restrict__ resid)
{
  extern __shared__ char smem[];
  constexpr int BUFSZ = 32768;  // A 16KB + B 16KB
  const int t = threadIdx.x, lane = t & 63, w = t >> 6;
  const int g = lane >> 4, l15 = lane & 15;
  const int wr = w >> 1, wc = w & 1;  // 2M x 2N waves; wave tile 64 x 64
  const int bid = blockIdx.x;
  const int tm = (bid & 7) * 8 + ((bid >> 3) & 7);
  const int tn = bid >> 6;
  const int m0 = tm << 7, n0 = tn << 7;

  const int srow = t >> 3;
  const int colswz = (((t & 7) ^ (srow & 7)) << 3);
  const unsigned short* pA = A + (size_t)(m0 + srow) * K + colswz;
  const unsigned short* pB = Bt + (size_t)(n0 + srow) * K + colswz;
  const int ldw = w << 10;

  auto stA = [&](int TT, char* buf) {
#pragma unroll
    for (int i = 0; i < 4; ++i)
      gld_lds16(pA + TT * 64 + (size_t)(i * 32) * K, buf + i * 4096 + ldw);
  };
  auto stB02 = [&](int TT, char* buf) {
    gld_lds16(pB + TT * 64, buf + 16384 + ldw);
    gld_lds16(pB + TT * 64 + (size_t)64 * K, buf + 16384 + 8192 + ldw);
  };
  auto stB13 = [&](int TT, char* buf) {
    gld_lds16(pB + TT * 64 + (size_t)32 * K, buf + 16384 + 4096 + ldw);
    gld_lds16(pB + TT * 64 + (size_t)96 * K, buf + 16384 + 12288 + ldw);
  };

  const int sw0 = (((0 + g) ^ (l15 & 7)) << 4);
  const int sw1 = (((4 + g) ^ (l15 & 7)) << 4);
  const int NT = K >> 6;

  f32x4 acc[4][4] = {};
  bf16x8 av[4][2], bv0[2][2], bv1[2][2];

#define LDA_ALL(CB) { _Pragma("unroll") for (int mi = 0; mi < 4; ++mi) {                  \
    const int row_ = (wr * 64 + mi * 16 + l15) * 128;                                     \
    av[mi][0] = *(const bf16x8*)((CB) + row_ + sw0);                                      \
    av[mi][1] = *(const bf16x8*)((CB) + row_ + sw1); } }
#define LDB_H(CB, H, BV) { _Pragma("unroll") for (int ni = 0; ni < 2; ++ni) {             \
    const int row_ = 16384 + (wc * 64 + (H) * 32 + ni * 16 + l15) * 128;                  \
    BV[ni][0] = *(const bf16x8*)((CB) + row_ + sw0);                                      \
    BV[ni][1] = *(const bf16x8*)((CB) + row_ + sw1); } }
#define MMH(BV, H) { __builtin_amdgcn_s_setprio(1);                                       \
    _Pragma("unroll") for (int mi = 0; mi < 4; ++mi)                                      \
      _Pragma("unroll") for (int ni = 0; ni < 2; ++ni) {                                  \
        acc[mi][(H)*2+ni] = MFMA_BF16(av[mi][0], BV[ni][0], acc[mi][(H)*2+ni]);           \
        acc[mi][(H)*2+ni] = MFMA_BF16(av[mi][1], BV[ni][1], acc[mi][(H)*2+ni]);  }        \
    __builtin_amdgcn_s_setprio(0); }

  // prologue: full tile 0 (8 ops) + tile 1's A,B02 (6 ops); prove tile 0
  stA(0, smem); stB02(0, smem); stB13(0, smem);
  stA(1, smem + BUFSZ); stB02(1, smem + BUFSZ);
  VMCNT(6);
  BAR();

  for (int kt = 0; kt < NT; ++kt) {
    char* cb = smem + (kt & 1) * BUFSZ;
    char* ob = smem + ((kt & 1) ^ 1) * BUFSZ;
    LDA_ALL(cb);
    LDB_H(cb, 0, bv0);
    if (kt + 1 < NT) stB13(kt + 1, ob);
    BAR();
    MMH(bv0, 0);
    BAR();
    LDB_H(cb, 1, bv1);
    if (kt + 2 < NT) { stA(kt + 2, cb); stB02(kt + 2, cb); VMCNT(6); }
    else if (kt + 1 < NT) VMCNT(0);
    BAR();
    MMH(bv1, 1);
    BAR();
  }
#undef LDA_ALL
#undef LDB_H
#undef MMH

  if constexpr (EPI == 2) {
#pragma unroll
    for (int mi = 0; mi < 4; ++mi) {
      const int ro = mi * 16 + g * 4;
#pragma unroll
      for (int ci = 0; ci < 4; ++ci) {
        const int n = n0 + wc * 64 + ((ci >> 1) << 5) + ((ci & 1) << 4) + l15;
        const float bn = bias[n];
#pragma unroll
        for (int r = 0; r < 4; ++r) {
          const size_t m = m0 + wr * 64 + ro + r;
          outf[m * N + n] = acc[mi][ci][r] + bn + resid[m * N + n];
        }
      }
    }
  } else if constexpr (EPI == 1) {  // transposed store for V
    __syncthreads();
    unsigned short* T = (unsigned short*)(smem + w * 9216);  // [64 n][72 m-padded]
#pragma unroll
    for (int mi = 0; mi < 4; ++mi)
#pragma unroll
      for (int ci = 0; ci < 4; ++ci) {
        const int co = ((ci >> 1) << 5) + ((ci & 1) << 4);
#pragma unroll
        for (int r = 0; r < 4; ++r)
          T[(co + l15) * 72 + mi * 16 + 4 * g + r] = bf16rn(acc[mi][ci][r]);
      }
    asm volatile("s_waitcnt lgkmcnt(0)" ::: "memory");
    const int bidx = m0 >> 11;
    const int srw = (m0 & 2047) + wr * 64 + ((lane & 7) << 3);
#pragma unroll
    for (int rr = 0; rr < 8; ++rr) {
      const int trow = rr * 8 + (lane >> 3);
      bf16x8 v = *(const bf16x8*)((char*)T + trow * 144 + ((lane & 7) << 4));
      *(bf16x8*)(outb + (size_t)(bidx * 1024 + n0 + wc * 64 + trow) * 2048 + srw) = v;
    }
  } else {  // EPI 0 / 3: bf16 store via rotated bounce (conflict-free writes)
    __syncthreads();
    char* wsl = smem + w * 8192;  // per-wave bounce [64 rows][128B, rows byte-rotated]
#pragma unroll
    for (int mi = 0; mi < 4; ++mi) {
      const int ro = mi * 16 + g * 4;
#pragma unroll
      for (int ci = 0; ci < 4; ++ci) {
        const int co = ((ci >> 1) << 5) + ((ci & 1) << 4) + l15;
        float bn = 0.f;
        if constexpr (EPI == 3) bn = bias[n0 + wc * 64 + co];
#pragma unroll
        for (int r = 0; r < 4; ++r) {
          float v = acc[mi][ci][r];
          if constexpr (EPI == 3) {
            v += bn;
            // gelu(u) = u / (1 + exp2(-2.3022085*(u+0.044715u^3)))
            const float inner = v + 0.044715f * v * v * v;
            const float s = exp2f(-2.3022085f * inner);
            v = v / (1.0f + s);
          }
          *(unsigned short*)(wsl + (ro + r) * 128 + ((co * 2 + g * 32) & 127)) = bf16rn(v);
        }
      }
    }
    // same-wave LDS RAW ordered by compiler lgkmcnt; rotation cancels: chunk c -> cols c*8..+7
#pragma unroll
    for (int s = 0; s < 8; ++s) {
      const int row = s * 8 + (lane >> 3);
      bf16x8 vv = *(const bf16x8*)(wsl + row * 128 +
                                   (((lane & 7) * 16 + ((row >> 2) & 3) * 32) & 127));
      *(bf16x8*)(outb + (size_t)(m0 + wr * 64 + row) * N + n0 + wc * 64 + (lane & 7) * 8) = vv;
    }
  }
}

// ---------------- flash attention, causal, D=64, QB=128 (8 waves x 16 rows), KB=64 --------
__global__ __launch_bounds__(512) void attn_kernel(
    const unsigned short* __restrict__ qg, const unsigned short* __restrict__ kg,
    const unsigned short* __restrict__ vT, unsigned short* __restrict__ ctx)
{
  __shared__ char smem[36864];  // K 8KB | V 8KB | Pt 8 x 2560
  const int bh = blockIdx.x, b = bh >> 4, h = bh & 15;
  const int t = threadIdx.x, lane = t & 63, w = t >> 6, g = lane >> 4, l15 = lane & 15;
  char* Ks = smem;
  char* Vs = smem + 8192;
  char* Pt = smem + 16384 + w * 2560;  // per-wave [64 kv][40B]

  const float SC = 0.18033688011112042f;  // 0.125 * log2(e)

  const int srow = t >> 3;
  const int ssw = ((((t & 7) << 4) ^ ((srow & 7) << 4)) >> 1);

  for (int pass = 0; pass < 2; ++pass) {
    const int qt = pass ? 15 - (int)blockIdx.y : (int)blockIdx.y;
    const int q0 = qt << 7;
    const int q0w = q0 + w * 16;

    bf16x8 qf[2];
#pragma unroll
    for (int ks = 0; ks < 2; ++ks)
      qf[ks] = *(const bf16x8*)(qg + (size_t)(b * 2048 + q0w + l15) * 2048 +
                                h * 64 + ks * 32 + g * 8);

    f32x4 acc[4] = {};
    float lsum[4] = {};

    const int ntile = 2 * qt + 2;
    for (int kt = 0; kt < ntile; ++kt) {
      const int kv0 = kt << 6;
      __syncthreads();
      gld_lds16(kg + (size_t)(b * 2048 + kv0 + srow) * 2048 + h * 64 + ssw,
                Ks + ((t >> 3) << 7));
      gld_lds16(vT + (size_t)(b * 1024 + h * 64 + srow) * 2048 + kv0 + ssw,
                Vs + ((t >> 3) << 7));
      __syncthreads();

      f32x4 sf[4] = {};
#pragma unroll
      for (int nb = 0; nb < 4; ++nb) {
        const int krow = nb * 16 + l15;
#pragma unroll
        for (int ks = 0; ks < 2; ++ks) {
          bf16x8 kf = *(const bf16x8*)(Ks + krow * 128 +
                                       (((ks * 32 + g * 8) << 1) ^ ((krow & 7) << 4)));
          sf[nb] = MFMA_BF16(qf[ks], kf, sf[nb]);
        }
      }
      if (kv0 + 63 > q0w) {  // causal mask (wave-uniform branch)
#pragma unroll
        for (int nb = 0; nb < 4; ++nb)
#pragma unroll
          for (int r = 0; r < 4; ++r) {
            const int qq = q0w + 4 * g + r;
            const int kk = kv0 + nb * 16 + l15;
            if (kk > qq) sf[nb][r] = -__builtin_inff();
          }
      }
#pragma unroll
      for (int nb = 0; nb < 4; ++nb)
#pragma unroll
        for (int r = 0; r < 4; ++r) {
          const float p = exp2f(__builtin_fmaf(sf[nb][r], SC, -4.0f));
          sf[nb][r] = p;
          lsum[r] += p;
        }
#pragma unroll
      for (int nb = 0; nb < 4; ++nb) {
        uint2v dw;
        asm("v_cvt_pk_bf16_f32 %0, %1, %2"
            : "=v"(dw.x) : "v"(sf[nb][0]), "v"(sf[nb][1]));
        asm("v_cvt_pk_bf16_f32 %0, %1, %2"
            : "=v"(dw.y) : "v"(sf[nb][2]), "v"(sf[nb][3]));
        *(uint2v*)(Pt + (nb * 16 + l15) * 40 + (g << 3)) = dw;
      }
      asm volatile("s_waitcnt lgkmcnt(0)" ::: "memory");  // same-wave P RAW
#pragma unroll
      for (int ks = 0; ks < 2; ++ks) {
        const char* pp = Pt + (ks * 32 + g * 8) * 40 + (l15 << 1);
        bf16x8 pa;
#pragma unroll
        for (int jj = 0; jj < 8; ++jj)
          pa[jj] = *(const short*)(pp + jj * 40);
#pragma unroll
        for (int nb = 0; nb < 4; ++nb) {
          const int drow = nb * 16 + l15;
          bf16x8 vb = *(const bf16x8*)(Vs + drow * 128 +
                                       (((ks * 32 + g * 8) << 1) ^ ((drow & 7) << 4)));
          acc[nb] = MFMA_BF16(pa, vb, acc[nb]);
        }
      }
    }
#pragma unroll
    for (int r = 0; r < 4; ++r) {
      float s = lsum[r];
      s += __shfl_xor(s, 1);
      s += __shfl_xor(s, 2);
      s += __shfl_xor(s, 4);
      s += __shfl_xor(s, 8);
      lsum[r] = s;
    }
    float inv[4];
#pragma unroll
    for (int r = 0; r < 4; ++r) inv[r] = 1.0f / lsum[r];
#pragma unroll
    for (int nb = 0; nb < 4; ++nb)
#pragma unroll
      for (int r = 0; r < 4; ++r)
        ctx[(size_t)(b * 2048 + q0w + 4 * g + r) * 1024 + h * 64 + nb * 16 + l15] =
            bf16rn(acc[nb][r] * inv[r]);
  }
}

extern "C" void kernel_launch(void* const* d_in, const int* in_sizes, int n_in,
                              void* d_out, int out_size, void* d_ws, size_t ws_size,
                              hipStream_t stream)
{
  const float* x   = (const float*)d_in[0];
  const float* l1s = (const float*)d_in[1];
  const float* l1b = (const float*)d_in[2];
  const float* l2s = (const float*)d_in[3];
  const float* l2b = (const float*)d_in[4];
  const float* Wq  = (const float*)d_in[5];
  const float* Wk  = (const float*)d_in[6];
  const float* Wv  = (const float*)d_in[7];
  const float* Wo  = (const float*)d_in[8];
  const float* bo  = (const float*)d_in[9];
  const float* Wfc = (const float*)d_in[10];
  const float* bfc = (const float*)d_in[11];
  const float* Wpj = (const float*)d_in[12];
  const float* bpj = (const float*)d_in[13];
  float* out = (float*)d_out;
  char* ws = (char*)d_ws;

  unsigned short* wT   = (unsigned short*)ws;                // 24MB weights
  unsigned short* wqkT = wT;                                 // [2048][1024] fused Q|K
  unsigned short* wvT  = wT + 2097152u;
  unsigned short* woT  = wT + 3145728u;
  unsigned short* wfcT = wT + 4194304u;
  unsigned short* wpjT = wT + 8388608u;
  unsigned short* ln1x = (unsigned short*)(ws + 25165824u);  // 16MB
  unsigned short* qkb  = (unsigned short*)(ws + 41943040u);  // 32MB [8192][2048]
  unsigned short* vTb  = (unsigned short*)(ws + 75497472u);  // 16MB
  unsigned short* ctx  = (unsigned short*)(ws + 92274688u);  // 16MB (reused as ln2x)
  unsigned short* ln2x = ctx;
  float* hbuf          = (float*)(ws + 109051904u);          // 32MB
  unsigned short* fcb  = (unsigned short*)(ws + 25165824u);  // 64MB, reuses ln1x..vTb

  convT_kernel<<<3072, 256, 0, stream>>>(Wq, Wk, Wv, Wo, Wfc, Wpj, wT);
  ln_kernel<<<8192, 256, 0, stream>>>(x, l1s, l1b, ln1x);
  g128<0><<<1024, 256, 65536, stream>>>(ln1x, wqkT, 2048, 1024,
                                        qkb, nullptr, nullptr, nullptr);
  g128<1><<<512, 256, 65536, stream>>>(ln1x, wvT, 1024, 1024,
                                       vTb, nullptr, nullptr, nullptr);
  attn_kernel<<<dim3(64, 8), 512, 0, stream>>>(qkb, qkb + 1024, vTb, ctx);
  g128<2><<<512, 256, 65536, stream>>>(ctx, woT, 1024, 1024,
                                       nullptr, hbuf, bo, x);
  ln_kernel<<<8192, 256, 0, stream>>>(hbuf, l2s, l2b, ln2x);
  g128<3><<<2048, 256, 65536, stream>>>(ln2x, wfcT, 4096, 1024,
                                        fcb, nullptr, bfc, nullptr);
  g128<2><<<512, 256, 65536, stream>>>(fcb, wpjT, 1024, 4096,
                                       nullptr, out, bpj, hbuf);
}